// Round 12
// baseline (1404.225 us; speedup 1.0000x reference)
//
#include <hip/hip_runtime.h>
#include <hip/hip_bf16.h>

// Problem constants: B=2, S=2048, HID=2048, H=16, HD=128, HD2=64, LAT=256
#define BB 2
#define SS 2048
#define HID 2048
#define NH 16
#define BS (BB*SS)          // 4096 rows
#define SCALE 0.088388347648318447f   // 1/sqrt(128)
#define C2LOG 0.12751743f              // SCALE * log2(e)

typedef __bf16 bf16x8 __attribute__((ext_vector_type(8)));
typedef float f32x4 __attribute__((ext_vector_type(4)));
typedef float f32x16 __attribute__((ext_vector_type(16)));
typedef unsigned int uintx2 __attribute__((ext_vector_type(2)));

__device__ __forceinline__ bf16x8 ld_frag(const __hip_bfloat16* p) {
    uint4 u = *reinterpret_cast<const uint4*>(p);
    return __builtin_bit_cast(bf16x8, u);
}
// HW packed f32->bf16 convert (RNE). gfx950 has no builtin (m240): inline asm.
__device__ __forceinline__ unsigned int cvt_pk_bf16(float a, float b) {
    unsigned int r;
    asm("v_cvt_pk_bf16_f32 %0, %1, %2" : "=v"(r) : "v"(a), "v"(b));
    return r;
}
__device__ __forceinline__ ushort bf_bits(float v) {
    return (ushort)cvt_pk_bf16(v, v);
}
__device__ __forceinline__ void store_c(__hip_bfloat16* C, size_t idx, float v) {
    *reinterpret_cast<ushort*>(&C[idx]) = bf_bits(v);
}
__device__ __forceinline__ void store_c(float* C, size_t idx, float v) {
    C[idx] = v;
}

// async global->LDS, 16B per lane; lds addr must be wave-uniform base + lane*16
#define GLD16(gp, lp) \
  __builtin_amdgcn_global_load_lds((const __attribute__((address_space(1))) void*)(gp), \
                                   (__attribute__((address_space(3))) void*)(lp), 16, 0, 0)

// ---------------------------------------------------------------------------
// Fragment-order global layouts (v13, kept).
// Kf: element K[b][kv][h][d] ->
//   (b*16+h)*262144 + (kv>>5)*4096 + (d>>4)*512 + ((d>>3)&1)*256 + (kv&31)*8 + (d&7)
// Vf: element V[b][kv][h][d] ->
//   (b*16+h)*262144 + (kv>>6)*8192 + (d>>5)*2048 + ((kv>>4)&3)*512
//   + ((kv>>3)&1)*256 + (d&31)*8 + (kv&7)
// ---------------------------------------------------------------------------

// ---------------------------------------------------------------------------
// prep kernel = weight transpose (blocks 0..8447) + hs fp32->bf16 convert
// (blocks 8448..12543). Block-uniform branch; one launch instead of two.
// ---------------------------------------------------------------------------
__global__ __launch_bounds__(256) void prep_kernel(
    const float* s0, const float* s1, const float* s2, const float* s3,
    const float* s4, const float* s5, const float* s6, const float* s7,
    __hip_bfloat16* WT1, __hip_bfloat16* WT2, __hip_bfloat16* WT3,
    __hip_bfloat16* WTo,
    const float* hs, __hip_bfloat16* hsb)
{
    if (blockIdx.x >= 8448) {
        // convert path: 4096 blocks x 256 threads = 1048576 = BS*HID/8 exact
        int i = (blockIdx.x - 8448) * 256 + threadIdx.x;
        float4 a = reinterpret_cast<const float4*>(hs)[2 * i];
        float4 b = reinterpret_cast<const float4*>(hs)[2 * i + 1];
        uint4 o;
        o.x = cvt_pk_bf16(a.x, a.y);
        o.y = cvt_pk_bf16(a.z, a.w);
        o.z = cvt_pk_bf16(b.x, b.y);
        o.w = cvt_pk_bf16(b.z, b.w);
        reinterpret_cast<uint4*>(hsb)[i] = o;
        return;
    }

    const float* srcs[8] = { s0, s1, s2, s3, s4, s5, s6, s7 };
    const int Rs[8] = { 2048, 2048, 2048, 256, 256, 256, 256, 2048 };
    const int Cs[8] = { 256, 256, 1024, 1024, 2048, 1024, 1024, 2048 };
    __hip_bfloat16* dsts[8] = {
        WT1, WT1 + (size_t)256 * 2048, WT1 + (size_t)512 * 2048,
        WT2, WT2 + (size_t)1024 * 256,
        WT3, WT3 + (size_t)1024 * 256,
        WTo };
    const int prefix[9] = { 0, 512, 1024, 3072, 3328, 3840, 4096, 4352, 8448 };

    int bid = blockIdx.x;
    int seg = 0;
    #pragma unroll
    for (int i = 0; i < 8; i++) if (bid >= prefix[i + 1]) seg = i + 1;
    int local = bid - prefix[seg];
    int R = Rs[seg], C = Cs[seg];
    int tilesC = C / 32;
    int tr = local / tilesC, tc = local % tilesC;
    int r0 = tr * 32, c0 = tc * 32;
    const float* src = srcs[seg];
    __hip_bfloat16* dst = dsts[seg];

    __shared__ float Ts[32][33];
    int t = threadIdx.x;
    int ty = t >> 5, tx = t & 31;
    #pragma unroll
    for (int k = 0; k < 4; k++) {
        int r = ty + k * 8;
        Ts[r][tx] = src[(size_t)(r0 + r) * C + c0 + tx];
    }
    __syncthreads();
    #pragma unroll
    for (int k = 0; k < 4; k++) {
        int r = ty + k * 8;
        *reinterpret_cast<ushort*>(&dst[(size_t)(c0 + r) * R + r0 + tx]) =
            bf_bits(Ts[tx][r]);
    }
}

// ---------------------------------------------------------------------------
// m97-style GEMM: C = A[M,K] * Bt[N,K]^T, bf16 in, fp32 acc.
// 128x128 tile, BK=32, global_load_lds staging, 4 waves each 64x64.
// + bijective XCD swizzle (T1; all grids here have nwg%8==0).
// Epilogue routing: col < splitN -> (C0,...) else (C1,...). cm = output scale.
//   s64==0: plain col
//   s64==1: col c -> (c>>6)*128 + (c&63) + off (head scatter, row-major)
//   s64==2: transposed store: Cp[c*4096 + row]
//   s64==3: Kf fragment-order scatter; c: h=c>>6, d=off+(c&63); row m: b,kv
//   s64==4: Vf fragment-order scatter; c: h=c>>7, d=c&127;    row m: b,kv
//   s64==5 (C1 only): Kf scatter + FUSED ROPE — pairs acc[mt][nt]/(nt+2)
//     (d=64+i / d=96+i land in same lane, cols 32 apart; splitN%128==0 makes
//      routing block-uniform). Rotation on fp32 acc, one bf16 rounding.
//   s64==6 (C1 only): head scatter row-major + FUSED ROPE (Q rope half).
// r11: rope kernel deleted; its RMW round-trip and launch are gone.
// ---------------------------------------------------------------------------
template <typename TC>
__global__ __launch_bounds__(256) void gemm_bt_kernel(
    const __hip_bfloat16* __restrict__ A, int lda,
    const __hip_bfloat16* __restrict__ Bt,
    TC* __restrict__ C0, int ldc0, int sp0, int off0, float cm0,
    TC* __restrict__ C1, int ldc1, int sp1, int off1, float cm1,
    int splitN, int K)
{
    __shared__ alignas(16) __hip_bfloat16 As[128 * 32];
    __shared__ alignas(16) __hip_bfloat16 Bs[128 * 32];

    // XCD-aware bijective remap (nwg % 8 == 0 for all launches here)
    const int nwg = gridDim.x * gridDim.y;
    int lin = blockIdx.y * gridDim.x + blockIdx.x;
    lin = (lin & 7) * (nwg >> 3) + (lin >> 3);
    const int bn = (lin % gridDim.x) * 128;
    const int bm = (lin / gridDim.x) * 128;

    const int t = threadIdx.x;
    const int w = t >> 6;
    const int lane = t & 63;
    const int l15 = lane & 15;
    const int quad = lane >> 4;
    const int wm = (w & 1) * 64;
    const int wn = (w >> 1) * 64;

    const int srow = lane >> 2;          // 0..15
    const int skcol = (lane & 3) * 8;    // 0,8,16,24

    f32x4 acc[4][4] = {};

    for (int k0 = 0; k0 < K; k0 += 32) {
        __syncthreads();
        #pragma unroll
        for (int i = 0; i < 2; i++) {
            int r = w * 32 + i * 16 + srow;
            GLD16(A + (size_t)(bm + r) * lda + k0 + skcol, &As[r * 32 + skcol]);
            GLD16(Bt + (size_t)(bn + r) * K + k0 + skcol, &Bs[r * 32 + skcol]);
        }
        __syncthreads();

        bf16x8 af[4], bf[4];
        #pragma unroll
        for (int mt = 0; mt < 4; mt++)
            af[mt] = ld_frag(&As[(wm + mt * 16 + l15) * 32 + quad * 8]);
        #pragma unroll
        for (int nt = 0; nt < 4; nt++)
            bf[nt] = ld_frag(&Bs[(wn + nt * 16 + l15) * 32 + quad * 8]);
        #pragma unroll
        for (int mt = 0; mt < 4; mt++)
            #pragma unroll
            for (int nt = 0; nt < 4; nt++)
                acc[mt][nt] = __builtin_amdgcn_mfma_f32_16x16x32_bf16(
                    af[mt], bf[nt], acc[mt][nt], 0, 0, 0);
    }

    if ((sp1 == 5 || sp1 == 6) && bn >= splitN) {
        // ---- rope-fused epilogue (whole block routes to C1) ----
        #pragma unroll
        for (int nt = 0; nt < 2; nt++) {
            const int c = bn + wn + nt * 16 + l15 - splitN;
            const int hh = c >> 6;
            const int i = c & 31;           // c&63 = nt*16+l15 < 32
            const float inv = exp2f(-(float)i * 0.4152410118609203f);
            #pragma unroll
            for (int mt = 0; mt < 4; mt++) {
                #pragma unroll
                for (int r = 0; r < 4; r++) {
                    const int m = bm + wm + mt * 16 + quad * 4 + r;
                    const int bb2 = m >> 11, kv = m & 2047;   // kv == seq pos
                    const float ang = (float)kv * inv;
                    const float sn = sinf(ang), cs = cosf(ang);
                    const float x1 = acc[mt][nt][r] * cm1;
                    const float x2 = acc[mt][nt + 2][r] * cm1;
                    const float o1 = x1 * cs - x2 * sn;
                    const float o2 = x1 * sn + x2 * cs;
                    if (sp1 == 5) {
                        const int d1 = 64 + i;
                        size_t idx1 = (size_t)(bb2 * 16 + hh) * 262144
                                    + (size_t)(kv >> 5) * 4096
                                    + (size_t)(kv & 31) * 8
                                    + (size_t)(d1 >> 4) * 512
                                    + (size_t)((d1 >> 3) & 1) * 256 + (d1 & 7);
                        store_c(C1, idx1, o1);
                        store_c(C1, idx1 + 1024, o2);   // d+32: +2 regions
                    } else {
                        const int oc = hh * 128 + 64 + i;
                        store_c(C1, (size_t)m * ldc1 + oc, o1);
                        store_c(C1, (size_t)m * ldc1 + oc + 32, o2);
                    }
                }
            }
        }
        return;
    }

    #pragma unroll
    for (int nt = 0; nt < 4; nt++) {
        int col = bn + wn + nt * 16 + l15;
        TC* Cp; int c, ld, s64, off; float cm;
        if (col < splitN) { Cp = C0; c = col; ld = ldc0; s64 = sp0; off = off0; cm = cm0; }
        else { Cp = C1; c = col - splitN; ld = ldc1; s64 = sp1; off = off1; cm = cm1; }
        if (s64 == 2) {
            #pragma unroll
            for (int mt = 0; mt < 4; mt++) {
                int row0 = bm + wm + mt * 16 + quad * 4;
                #pragma unroll
                for (int r = 0; r < 4; r++)
                    store_c(Cp, (size_t)c * 4096 + row0 + r, acc[mt][nt][r] * cm);
            }
        } else if (s64 == 3) {
            const int hh = c >> 6, d = off + (c & 63);
            const size_t dbase = (size_t)(d >> 4) * 512
                               + (size_t)((d >> 3) & 1) * 256 + (d & 7);
            #pragma unroll
            for (int mt = 0; mt < 4; mt++) {
                #pragma unroll
                for (int r = 0; r < 4; r++) {
                    int m = bm + wm + mt * 16 + quad * 4 + r;
                    int bb2 = m >> 11, kv = m & 2047;
                    size_t idx = (size_t)(bb2 * 16 + hh) * 262144
                               + (size_t)(kv >> 5) * 4096 + dbase
                               + (size_t)(kv & 31) * 8;
                    store_c(Cp, idx, acc[mt][nt][r] * cm);
                }
            }
        } else if (s64 == 4) {
            const int hh = c >> 7, d = c & 127;
            const size_t dbase = (size_t)(d >> 5) * 2048 + (size_t)(d & 31) * 8;
            #pragma unroll
            for (int mt = 0; mt < 4; mt++) {
                #pragma unroll
                for (int r = 0; r < 4; r++) {
                    int m = bm + wm + mt * 16 + quad * 4 + r;
                    int bb2 = m >> 11, kv = m & 2047;
                    size_t idx = (size_t)(bb2 * 16 + hh) * 262144
                               + (size_t)(kv >> 6) * 8192 + dbase
                               + (size_t)((kv >> 4) & 3) * 512
                               + (size_t)((kv >> 3) & 1) * 256 + (kv & 7);
                    store_c(Cp, idx, acc[mt][nt][r] * cm);
                }
            }
        } else {
            int oc = s64 ? ((c >> 6) * 128 + (c & 63) + off) : c;
            #pragma unroll
            for (int mt = 0; mt < 4; mt++) {
                #pragma unroll
                for (int r = 0; r < 4; r++) {
                    int row = bm + wm + mt * 16 + quad * 4 + r;
                    store_c(Cp, (size_t)row * ld + oc, acc[mt][nt][r] * cm);
                }
            }
        }
    }
}

// ---------------------------------------------------------------------------
// Flash attention v17 (REVERTED verbatim from r10 — 69.2us proven).
// r11 post-mortem: v18's kv-split forced VGPR cap 128 << ~230 working set ->
// VGPR_Count 64 + 820MB scratch spill traffic (WRITE_SIZE), 372us. The
// occupancy thesis cannot be funded from this kernel's register budget.
// ---------------------------------------------------------------------------
__global__ __launch_bounds__(512) void flash_attn_kernel(
    const __hip_bfloat16* __restrict__ Q,
    const __hip_bfloat16* __restrict__ Kf,
    const __hip_bfloat16* __restrict__ Vf,
    __hip_bfloat16* __restrict__ O)
{
    // XCD-grouped decode: same-(b,h) blocks share blockIdx.x -> same XCD.
    const int p = blockIdx.y & 7;                     // pair index 0..7
    const int h = blockIdx.x + 8 * (blockIdx.y >> 3); // head 0..15
    const int b = blockIdx.z;
    const int t = threadIdx.x;
    const int w = t >> 6;                // 0..7
    const int lane = t & 63;
    const int l31 = lane & 31;
    const int hi = lane >> 5;

    const int qt = (w < 4) ? (15 - p) : p;   // this wave's q-tile
    const int wq = w & 3;
    const int qwb = qt * 128 + wq * 32;      // wave's q base (32 rows)
    const int q = qwb + l31;                 // this lane's q row
    const int my_nt = 2 * qt + 1 + (wq >> 1);// kv tiles this wave needs

    const __hip_bfloat16* Kfb = Kf + (size_t)(b * 16 + h) * 262144;
    const __hip_bfloat16* Vfb = Vf + (size_t)(b * 16 + h) * 262144;

    // Q B-frags: qf[s] = Q[q][d = 16s + 8hi + j], j=0..7
    bf16x8 qf[8];
    {
        const __hip_bfloat16* qrow = Q + (size_t)(b * SS + q) * 2048 + h * 128;
        #pragma unroll
        for (int s = 0; s < 8; s++)
            qf[s] = ld_frag(qrow + s * 16 + hi * 8);
    }

    const int loff = lane * 8;               // fragment slot (elements)
    const __hip_bfloat16* kptr = Kfb + loff; // region (kb*8+s)*512 per tile
    const __hip_bfloat16* vptr = Vfb + loff; // region (dt*4+s)*512 per tile

    float m_i = -INFINITY;   // running max, log2 domain (S * C2LOG)
    float l_i = 0.0f;
    f32x16 acc[4] = {};      // O^T: acc[dt], d = dt*32 + 8*(e>>2) + 4hi + (e&3), col q=l31

    for (int kt = 0; kt < my_nt; kt++) {
        const int kvb = kt * 64;

        // ---- K fragments: 16 coalesced 16B/lane loads straight from L2 ----
        bf16x8 kfr[2][8];
        #pragma unroll
        for (int kb = 0; kb < 2; kb++)
            #pragma unroll
            for (int s = 0; s < 8; s++)
                kfr[kb][s] = ld_frag(kptr + (kb * 8 + s) * 512);

        // ---- S^T = K * Q^T : 2 kv-blocks x 8 k-steps of 32x32x16 ----
        f32x16 st[2] = {};
        __builtin_amdgcn_s_setprio(1);
        #pragma unroll
        for (int s = 0; s < 8; s++)
            #pragma unroll
            for (int kb = 0; kb < 2; kb++)
                st[kb] = __builtin_amdgcn_mfma_f32_32x32x16_bf16(
                    kfr[kb][s], qf[s], st[kb], 0, 0, 0);
        __builtin_amdgcn_s_setprio(0);

        // ---- V fragments issued now; land under softmax (T14) ----
        bf16x8 vfr[4][4];
        #pragma unroll
        for (int dt = 0; dt < 4; dt++)
            #pragma unroll
            for (int s = 0; s < 4; s++)
                vfr[dt][s] = ld_frag(vptr + (dt * 4 + s) * 512);

        // ---- row max; causal cndmask only on the diagonal tile ----
        float tmx;
        if (kvb + 63 > qwb) {            // wave-uniform: diagonal tile
            const int thr = q - kvb - 4 * hi;   // pass iff kb*32 + 8g + r <= thr
            tmx = -INFINITY;
            #pragma unroll
            for (int kb = 0; kb < 2; kb++)
                #pragma unroll
                for (int g = 0; g < 4; g++)
                    #pragma unroll
                    for (int r = 0; r < 4; r++) {
                        const int e = g * 4 + r;
                        float v = (kb * 32 + 8 * g + r <= thr) ? st[kb][e] : -INFINITY;
                        st[kb][e] = v;
                        tmx = fmaxf(tmx, v);
                    }
        } else {                          // interior: max3-fusible tree
            tmx = fmaxf(st[0][0], st[0][1]);
            #pragma unroll
            for (int e = 2; e < 16; e += 2)
                tmx = fmaxf(fmaxf(tmx, st[0][e]), st[0][e + 1]);
            #pragma unroll
            for (int e = 0; e < 16; e += 2)
                tmx = fmaxf(fmaxf(tmx, st[1][e]), st[1][e + 1]);
        }
        tmx = fmaxf(tmx, __shfl_xor(tmx, 32));
        const float m2x = tmx * C2LOG;

        // ---- online softmax (log2 domain) + T13 defer-max ----
        const bool nosc = __all(m2x <= m_i + 8.0f);
        const float mnew = nosc ? m_i : fmaxf(m_i, m2x);
        float rs = 0.0f;
        #pragma unroll
        for (int kb = 0; kb < 2; kb++)
            #pragma unroll
            for (int e = 0; e < 16; e++) {
                float pv = exp2f(fmaf(st[kb][e], C2LOG, -mnew));
                st[kb][e] = pv;
                rs += pv;
            }
        rs += __shfl_xor(rs, 32);
        if (!nosc) {
            const float alpha = exp2f(m_i - mnew);
            m_i = mnew;
            l_i *= alpha;
            #pragma unroll
            for (int dt = 0; dt < 4; dt++)
                #pragma unroll
                for (int e = 0; e < 16; e++)
                    acc[dt][e] *= alpha;
        }
        l_i += rs;

        // ---- P -> bf16 PV B-frags in registers (T12, HW cvt_pk) ----
        uint4 af[4];
        #pragma unroll
        for (int kb = 0; kb < 2; kb++) {
            unsigned int pk[4][2];
            #pragma unroll
            for (int g = 0; g < 4; g++)
                #pragma unroll
                for (int i = 0; i < 2; i++)
                    pk[g][i] = cvt_pk_bf16(st[kb][g * 4 + 2 * i],
                                           st[kb][g * 4 + 2 * i + 1]);
            #pragma unroll
            for (int sl = 0; sl < 2; sl++) {
                uintx2 r0 = __builtin_amdgcn_permlane32_swap(
                    pk[2 * sl][0], pk[2 * sl + 1][0], false, false);
                uintx2 r1 = __builtin_amdgcn_permlane32_swap(
                    pk[2 * sl][1], pk[2 * sl + 1][1], false, false);
                af[kb * 2 + sl] = make_uint4(r0[0], r1[0], r0[1], r1[1]);
            }
        }

        // ---- O^T += V^T * P^T : 4 d-tiles x 4 kv-steps ----
        __builtin_amdgcn_s_setprio(1);
        #pragma unroll
        for (int s = 0; s < 4; s++) {
            bf16x8 pf = __builtin_bit_cast(bf16x8, af[s]);
            #pragma unroll
            for (int dt = 0; dt < 4; dt++)
                acc[dt] = __builtin_amdgcn_mfma_f32_32x32x16_bf16(
                    vfr[dt][s], pf, acc[dt], 0, 0, 0);
        }
        __builtin_amdgcn_s_setprio(0);

        kptr += 8192; vptr += 8192;
    }

    // ---- epilogue: per-lane q = l31, d = dt*32 + 8g + 4hi + r ----
    const float inv_l = 1.0f / l_i;
    __hip_bfloat16* orow = O + (size_t)(b * SS + q) * 2048 + h * 128;
    #pragma unroll
    for (int dt = 0; dt < 4; dt++)
        #pragma unroll
        for (int g = 0; g < 4; g++) {
            uint2 uu;
            uu.x = cvt_pk_bf16(acc[dt][g * 4 + 0] * inv_l, acc[dt][g * 4 + 1] * inv_l);
            uu.y = cvt_pk_bf16(acc[dt][g * 4 + 2] * inv_l, acc[dt][g * 4 + 3] * inv_l);
            *reinterpret_cast<uint2*>(orow + dt * 32 + 8 * g + 4 * hi) = uu;
        }
}

// ---------------------------------------------------------------------------
extern "C" void kernel_launch(void* const* d_in, const int* in_sizes, int n_in,
                              void* d_out, int out_size, void* d_ws, size_t ws_size,
                              hipStream_t stream)
{
    const float* hs       = (const float*)d_in[0];
    const float* w_kv_d   = (const float*)d_in[1];
    const float* w_q_d    = (const float*)d_in[2];
    const float* w_k_u    = (const float*)d_in[3];
    const float* w_q_u    = (const float*)d_in[4];
    const float* w_v_u    = (const float*)d_in[5];
    const float* w_rope_k = (const float*)d_in[6];
    const float* w_rope_q = (const float*)d_in[7];
    const float* w_o      = (const float*)d_in[8];
    float* out = (float*)d_out;

    char* p = (char*)d_ws;
    auto alloc = [&](size_t nelem) {
        __hip_bfloat16* r = (__hip_bfloat16*)p;
        p += nelem * sizeof(__hip_bfloat16);
        return r;
    };
    __hip_bfloat16* hsb  = alloc((size_t)BS * HID);        // 16 MB (reused as attn)
    __hip_bfloat16* qkvd = alloc((size_t)BS * 512);        // 4 MB
    __hip_bfloat16* WT1  = alloc((size_t)1536 * 2048);     // 6 MB
    __hip_bfloat16* WT2  = alloc((size_t)3072 * 256);      // 1.5 MB
    __hip_bfloat16* WT3  = alloc((size_t)2048 * 256);      // 1 MB
    __hip_bfloat16* WTo  = alloc((size_t)2048 * 2048);     // 8 MB
    __hip_bfloat16* Kf   = alloc((size_t)BS * HID);        // 16 MB, fragment-order K
    __hip_bfloat16* Qbuf = alloc((size_t)BS * HID);        // 16 MB
    __hip_bfloat16* Vf   = alloc((size_t)HID * BS);        // 16 MB, fragment-order V
    __hip_bfloat16* attn = hsb;   // hs dead after G1

    dim3 blk(256);

    // 0. prep: weight transpose+convert (blocks 0..8447) + hs->bf16 (8448..)
    prep_kernel<<<dim3(12544), blk, 0, stream>>>(
        w_kv_d, w_q_d, w_rope_k, w_k_u, w_v_u, w_q_u, w_rope_q, w_o,
        WT1, WT2, WT3, WTo, hs, hsb);

    // G1: [kv_d | q_d | krp] = hsb @ WT1^T  (N=1536, K=2048);
    //     krp -> Kf d=64..127 with FUSED ROPE (mode 5)
    gemm_bt_kernel<__hip_bfloat16><<<dim3(1536 / 128, BS / 128), blk, 0, stream>>>(
        hsb, 2048, WT1,
        qkvd, 512, 0, 0, 1.0f,
        Kf, 0, 5, 64, 1.0f,
        512, 2048);
    // G2: [k_p | v] = kv_d @ WT2^T  (N=3072, K=256); k_p -> Kf d=0..63, v -> Vf
    gemm_bt_kernel<__hip_bfloat16><<<dim3(3072 / 128, BS / 128), blk, 0, stream>>>(
        qkvd, 512, WT2,
        Kf, 0, 3, 0, 1.0f,
        Vf, 0, 4, 0, 1.0f,
        1024, 256);
    // G3: [q_p | q_rope] = q_d @ WT3^T  (N=2048, K=256);
    //     q_rope -> Qbuf head-scatter with FUSED ROPE (mode 6)
    gemm_bt_kernel<__hip_bfloat16><<<dim3(2048 / 128, BS / 128), blk, 0, stream>>>(
        qkvd + 256, 512, WT3,
        Qbuf, 2048, 1, 0, 1.0f,
        Qbuf, 2048, 6, 64, 1.0f,
        1024, 256);
    // 4. flash attention v17 -> attn (no LDS, no barriers, direct L2 frags)
    flash_attn_kernel<<<dim3(8, NH, BB), dim3(512), 0, stream>>>(
        Qbuf, Kf, Vf, attn);
    // G4: out = attn @ WTo^T (fp32 out)
    gemm_bt_kernel<float><<<dim3(2048 / 128, BS / 128), blk, 0, stream>>>(
        attn, 2048, WTo,
        out, 2048, 0, 0, 1.0f,
        out, 2048, 0, 0, 1.0f,
        2048, 2048);
}

// Round 13
// 328.105 us; speedup vs baseline: 4.2798x; 4.2798x over previous
//
#include <hip/hip_runtime.h>
#include <hip/hip_bf16.h>

// Problem constants: B=2, S=2048, HID=2048, H=16, HD=128, HD2=64, LAT=256
#define BB 2
#define SS 2048
#define HID 2048
#define NH 16
#define BS (BB*SS)          // 4096 rows
#define SCALE 0.088388347648318447f   // 1/sqrt(128)
#define C2LOG 0.12751743f              // SCALE * log2(e)

typedef __bf16 bf16x8 __attribute__((ext_vector_type(8)));
typedef float f32x4 __attribute__((ext_vector_type(4)));
typedef float f32x16 __attribute__((ext_vector_type(16)));
typedef unsigned int uintx2 __attribute__((ext_vector_type(2)));

__device__ __forceinline__ bf16x8 ld_frag(const __hip_bfloat16* p) {
    uint4 u = *reinterpret_cast<const uint4*>(p);
    return __builtin_bit_cast(bf16x8, u);
}
// HW packed f32->bf16 convert (RNE). gfx950 has no builtin (m240): inline asm.
__device__ __forceinline__ unsigned int cvt_pk_bf16(float a, float b) {
    unsigned int r;
    asm("v_cvt_pk_bf16_f32 %0, %1, %2" : "=v"(r) : "v"(a), "v"(b));
    return r;
}
__device__ __forceinline__ ushort bf_bits(float v) {
    return (ushort)cvt_pk_bf16(v, v);
}
__device__ __forceinline__ void store_c(__hip_bfloat16* C, size_t idx, float v) {
    *reinterpret_cast<ushort*>(&C[idx]) = bf_bits(v);
}
__device__ __forceinline__ void store_c(float* C, size_t idx, float v) {
    C[idx] = v;
}

// async global->LDS, 16B per lane; lds addr must be wave-uniform base + lane*16
#define GLD16(gp, lp) \
  __builtin_amdgcn_global_load_lds((const __attribute__((address_space(1))) void*)(gp), \
                                   (__attribute__((address_space(3))) void*)(lp), 16, 0, 0)

// ---------------------------------------------------------------------------
// Fragment-order global layouts (v13, kept).
// Kf: element K[b][kv][h][d] ->
//   (b*16+h)*262144 + (kv>>5)*4096 + (d>>4)*512 + ((d>>3)&1)*256 + (kv&31)*8 + (d&7)
// Vf: element V[b][kv][h][d] ->
//   (b*16+h)*262144 + (kv>>6)*8192 + (d>>5)*2048 + ((kv>>4)&3)*512
//   + ((kv>>3)&1)*256 + (d&31)*8 + (kv&7)
// ---------------------------------------------------------------------------

// ---------------------------------------------------------------------------
// prep kernel = weight transpose (blocks 0..8447) + hs fp32->bf16 convert
// (blocks 8448..12543). Block-uniform branch; one launch instead of two.
// (r12 post-mortem: this fusion was benign; the ROPE-in-GEMM fusion was the
//  disaster — sinf/cosf epilogue spilled the whole GEMM to scratch, 2GB
//  WRITE_SIZE, 525us/dispatch. Reverted; rope is a standalone kernel again.)
// ---------------------------------------------------------------------------
__global__ __launch_bounds__(256) void prep_kernel(
    const float* s0, const float* s1, const float* s2, const float* s3,
    const float* s4, const float* s5, const float* s6, const float* s7,
    __hip_bfloat16* WT1, __hip_bfloat16* WT2, __hip_bfloat16* WT3,
    __hip_bfloat16* WTo,
    const float* hs, __hip_bfloat16* hsb)
{
    if (blockIdx.x >= 8448) {
        // convert path: 4096 blocks x 256 threads = 1048576 = BS*HID/8 exact
        int i = (blockIdx.x - 8448) * 256 + threadIdx.x;
        float4 a = reinterpret_cast<const float4*>(hs)[2 * i];
        float4 b = reinterpret_cast<const float4*>(hs)[2 * i + 1];
        uint4 o;
        o.x = cvt_pk_bf16(a.x, a.y);
        o.y = cvt_pk_bf16(a.z, a.w);
        o.z = cvt_pk_bf16(b.x, b.y);
        o.w = cvt_pk_bf16(b.z, b.w);
        reinterpret_cast<uint4*>(hsb)[i] = o;
        return;
    }

    const float* srcs[8] = { s0, s1, s2, s3, s4, s5, s6, s7 };
    const int Rs[8] = { 2048, 2048, 2048, 256, 256, 256, 256, 2048 };
    const int Cs[8] = { 256, 256, 1024, 1024, 2048, 1024, 1024, 2048 };
    __hip_bfloat16* dsts[8] = {
        WT1, WT1 + (size_t)256 * 2048, WT1 + (size_t)512 * 2048,
        WT2, WT2 + (size_t)1024 * 256,
        WT3, WT3 + (size_t)1024 * 256,
        WTo };
    const int prefix[9] = { 0, 512, 1024, 3072, 3328, 3840, 4096, 4352, 8448 };

    int bid = blockIdx.x;
    int seg = 0;
    #pragma unroll
    for (int i = 0; i < 8; i++) if (bid >= prefix[i + 1]) seg = i + 1;
    int local = bid - prefix[seg];
    int R = Rs[seg], C = Cs[seg];
    int tilesC = C / 32;
    int tr = local / tilesC, tc = local % tilesC;
    int r0 = tr * 32, c0 = tc * 32;
    const float* src = srcs[seg];
    __hip_bfloat16* dst = dsts[seg];

    __shared__ float Ts[32][33];
    int t = threadIdx.x;
    int ty = t >> 5, tx = t & 31;
    #pragma unroll
    for (int k = 0; k < 4; k++) {
        int r = ty + k * 8;
        Ts[r][tx] = src[(size_t)(r0 + r) * C + c0 + tx];
    }
    __syncthreads();
    #pragma unroll
    for (int k = 0; k < 4; k++) {
        int r = ty + k * 8;
        *reinterpret_cast<ushort*>(&dst[(size_t)(c0 + r) * R + r0 + tx]) =
            bf_bits(Ts[tx][r]);
    }
}

// ---------------------------------------------------------------------------
// m97-style GEMM: C = A[M,K] * Bt[N,K]^T, bf16 in, fp32 acc.
// 128x128 tile, BK=32, global_load_lds staging, 4 waves each 64x64.
// + bijective XCD swizzle (T1; all grids here have nwg%8==0).
// Epilogue routing: col < splitN -> (C0,...) else (C1,...). cm = output scale.
//   s64==0: plain col
//   s64==1: col c -> (c>>6)*128 + (c&63) + off (head scatter, row-major)
//   s64==2: transposed store: Cp[c*4096 + row]
//   s64==3: Kf fragment-order scatter; c: h=c>>6, d=off+(c&63); row m: b,kv
//   s64==4: Vf fragment-order scatter; c: h=c>>7, d=c&127;    row m: b,kv
// (r12: modes 5/6 rope-fusion REMOVED — scratch-spill catastrophe.)
// ---------------------------------------------------------------------------
template <typename TC>
__global__ __launch_bounds__(256) void gemm_bt_kernel(
    const __hip_bfloat16* __restrict__ A, int lda,
    const __hip_bfloat16* __restrict__ Bt,
    TC* __restrict__ C0, int ldc0, int sp0, int off0, float cm0,
    TC* __restrict__ C1, int ldc1, int sp1, int off1, float cm1,
    int splitN, int K)
{
    __shared__ alignas(16) __hip_bfloat16 As[128 * 32];
    __shared__ alignas(16) __hip_bfloat16 Bs[128 * 32];

    // XCD-aware bijective remap (nwg % 8 == 0 for all launches here)
    const int nwg = gridDim.x * gridDim.y;
    int lin = blockIdx.y * gridDim.x + blockIdx.x;
    lin = (lin & 7) * (nwg >> 3) + (lin >> 3);
    const int bn = (lin % gridDim.x) * 128;
    const int bm = (lin / gridDim.x) * 128;

    const int t = threadIdx.x;
    const int w = t >> 6;
    const int lane = t & 63;
    const int l15 = lane & 15;
    const int quad = lane >> 4;
    const int wm = (w & 1) * 64;
    const int wn = (w >> 1) * 64;

    const int srow = lane >> 2;          // 0..15
    const int skcol = (lane & 3) * 8;    // 0,8,16,24

    f32x4 acc[4][4] = {};

    for (int k0 = 0; k0 < K; k0 += 32) {
        __syncthreads();
        #pragma unroll
        for (int i = 0; i < 2; i++) {
            int r = w * 32 + i * 16 + srow;
            GLD16(A + (size_t)(bm + r) * lda + k0 + skcol, &As[r * 32 + skcol]);
            GLD16(Bt + (size_t)(bn + r) * K + k0 + skcol, &Bs[r * 32 + skcol]);
        }
        __syncthreads();

        bf16x8 af[4], bf[4];
        #pragma unroll
        for (int mt = 0; mt < 4; mt++)
            af[mt] = ld_frag(&As[(wm + mt * 16 + l15) * 32 + quad * 8]);
        #pragma unroll
        for (int nt = 0; nt < 4; nt++)
            bf[nt] = ld_frag(&Bs[(wn + nt * 16 + l15) * 32 + quad * 8]);
        #pragma unroll
        for (int mt = 0; mt < 4; mt++)
            #pragma unroll
            for (int nt = 0; nt < 4; nt++)
                acc[mt][nt] = __builtin_amdgcn_mfma_f32_16x16x32_bf16(
                    af[mt], bf[nt], acc[mt][nt], 0, 0, 0);
    }

    #pragma unroll
    for (int nt = 0; nt < 4; nt++) {
        int col = bn + wn + nt * 16 + l15;
        TC* Cp; int c, ld, s64, off; float cm;
        if (col < splitN) { Cp = C0; c = col; ld = ldc0; s64 = sp0; off = off0; cm = cm0; }
        else { Cp = C1; c = col - splitN; ld = ldc1; s64 = sp1; off = off1; cm = cm1; }
        if (s64 == 2) {
            #pragma unroll
            for (int mt = 0; mt < 4; mt++) {
                int row0 = bm + wm + mt * 16 + quad * 4;
                #pragma unroll
                for (int r = 0; r < 4; r++)
                    store_c(Cp, (size_t)c * 4096 + row0 + r, acc[mt][nt][r] * cm);
            }
        } else if (s64 == 3) {
            const int hh = c >> 6, d = off + (c & 63);
            const size_t dbase = (size_t)(d >> 4) * 512
                               + (size_t)((d >> 3) & 1) * 256 + (d & 7);
            #pragma unroll
            for (int mt = 0; mt < 4; mt++) {
                #pragma unroll
                for (int r = 0; r < 4; r++) {
                    int m = bm + wm + mt * 16 + quad * 4 + r;
                    int bb2 = m >> 11, kv = m & 2047;
                    size_t idx = (size_t)(bb2 * 16 + hh) * 262144
                               + (size_t)(kv >> 5) * 4096 + dbase
                               + (size_t)(kv & 31) * 8;
                    store_c(Cp, idx, acc[mt][nt][r] * cm);
                }
            }
        } else if (s64 == 4) {
            const int hh = c >> 7, d = c & 127;
            const size_t dbase = (size_t)(d >> 5) * 2048 + (size_t)(d & 31) * 8;
            #pragma unroll
            for (int mt = 0; mt < 4; mt++) {
                #pragma unroll
                for (int r = 0; r < 4; r++) {
                    int m = bm + wm + mt * 16 + quad * 4 + r;
                    int bb2 = m >> 11, kv = m & 2047;
                    size_t idx = (size_t)(bb2 * 16 + hh) * 262144
                               + (size_t)(kv >> 6) * 8192 + dbase
                               + (size_t)((kv >> 4) & 3) * 512
                               + (size_t)((kv >> 3) & 1) * 256 + (kv & 7);
                    store_c(Cp, idx, acc[mt][nt][r] * cm);
                }
            }
        } else {
            int oc = s64 ? ((c >> 6) * 128 + (c & 63) + off) : c;
            #pragma unroll
            for (int mt = 0; mt < 4; mt++) {
                #pragma unroll
                for (int r = 0; r < 4; r++) {
                    int row = bm + wm + mt * 16 + quad * 4 + r;
                    store_c(Cp, (size_t)row * ld + oc, acc[mt][nt][r] * cm);
                }
            }
        }
    }
}

// ---------------------------------------------------------------------------
// RoPE in-place: K in Kf fragment-order layout, Q in row-major Qbuf.
// Pair (d1=64+i, d2=96+i): in Kf, d2 is exactly +2 regions = +1024 elems.
// (Standalone again — r12 proved fusing this into the GEMM epilogue spills.)
// ---------------------------------------------------------------------------
__global__ __launch_bounds__(256) void rope_kernel(
    __hip_bfloat16* __restrict__ Kf, __hip_bfloat16* __restrict__ Qb)
{
    int idx = blockIdx.x * blockDim.x + threadIdx.x;
    if (idx >= BS * NH * 32) return;
    int i = idx & 31;
    int h = (idx >> 5) & 15;
    int row = idx >> 9;
    int s = row & (SS - 1);
    int b = row >> 11;

    float inv = exp2f(-(float)i * 0.4152410118609203f);  // 10000^(-i/32)
    float ang = (float)s * inv;
    float sn = sinf(ang), cs = cosf(ang);

    {   // K (Kf layout)
        size_t kaddr = ((size_t)(b * 16 + h) * 64 + (s >> 5)) * 4096
                     + (size_t)(4 + (i >> 4)) * 512
                     + (size_t)(((i >> 3) & 1) * 32 + (s & 31)) * 8 + (i & 7);
        float x1 = __bfloat162float(Kf[kaddr]);
        float x2 = __bfloat162float(Kf[kaddr + 1024]);
        *reinterpret_cast<ushort*>(&Kf[kaddr])        = bf_bits(x1 * cs - x2 * sn);
        *reinterpret_cast<ushort*>(&Kf[kaddr + 1024]) = bf_bits(x1 * sn + x2 * cs);
    }
    {   // Q (row-major)
        size_t obase = (size_t)row * 2048 + h * 128 + 64 + i;
        float x1 = __bfloat162float(Qb[obase]);
        float x2 = __bfloat162float(Qb[obase + 32]);
        *reinterpret_cast<ushort*>(&Qb[obase])      = bf_bits(x1 * cs - x2 * sn);
        *reinterpret_cast<ushort*>(&Qb[obase + 32]) = bf_bits(x1 * sn + x2 * cs);
    }
}

// ---------------------------------------------------------------------------
// Flash attention v17 (verbatim from the round-9 submission — 69.2us, VGPR
// 108, LDS 0, FETCH 24.6MB measured in r10, the best state).
// ---------------------------------------------------------------------------
__global__ __launch_bounds__(512) void flash_attn_kernel(
    const __hip_bfloat16* __restrict__ Q,
    const __hip_bfloat16* __restrict__ Kf,
    const __hip_bfloat16* __restrict__ Vf,
    __hip_bfloat16* __restrict__ O)
{
    // XCD-grouped decode: same-(b,h) blocks share blockIdx.x -> same XCD.
    const int p = blockIdx.y & 7;                     // pair index 0..7
    const int h = blockIdx.x + 8 * (blockIdx.y >> 3); // head 0..15
    const int b = blockIdx.z;
    const int t = threadIdx.x;
    const int w = t >> 6;                // 0..7
    const int lane = t & 63;
    const int l31 = lane & 31;
    const int hi = lane >> 5;

    const int qt = (w < 4) ? (15 - p) : p;   // this wave's q-tile
    const int wq = w & 3;
    const int qwb = qt * 128 + wq * 32;      // wave's q base (32 rows)
    const int q = qwb + l31;                 // this lane's q row
    const int my_nt = 2 * qt + 1 + (wq >> 1);// kv tiles this wave needs

    const __hip_bfloat16* Kfb = Kf + (size_t)(b * 16 + h) * 262144;
    const __hip_bfloat16* Vfb = Vf + (size_t)(b * 16 + h) * 262144;

    // Q B-frags: qf[s] = Q[q][d = 16s + 8hi + j], j=0..7
    bf16x8 qf[8];
    {
        const __hip_bfloat16* qrow = Q + (size_t)(b * SS + q) * 2048 + h * 128;
        #pragma unroll
        for (int s = 0; s < 8; s++)
            qf[s] = ld_frag(qrow + s * 16 + hi * 8);
    }

    const int loff = lane * 8;               // fragment slot (elements)
    const __hip_bfloat16* kptr = Kfb + loff; // region (kb*8+s)*512 per tile
    const __hip_bfloat16* vptr = Vfb + loff; // region (dt*4+s)*512 per tile

    float m_i = -INFINITY;   // running max, log2 domain (S * C2LOG)
    float l_i = 0.0f;
    f32x16 acc[4] = {};      // O^T: acc[dt], d = dt*32 + 8*(e>>2) + 4hi + (e&3), col q=l31

    for (int kt = 0; kt < my_nt; kt++) {
        const int kvb = kt * 64;

        // ---- K fragments: 16 coalesced 16B/lane loads straight from L2 ----
        bf16x8 kfr[2][8];
        #pragma unroll
        for (int kb = 0; kb < 2; kb++)
            #pragma unroll
            for (int s = 0; s < 8; s++)
                kfr[kb][s] = ld_frag(kptr + (kb * 8 + s) * 512);

        // ---- S^T = K * Q^T : 2 kv-blocks x 8 k-steps of 32x32x16 ----
        f32x16 st[2] = {};
        __builtin_amdgcn_s_setprio(1);
        #pragma unroll
        for (int s = 0; s < 8; s++)
            #pragma unroll
            for (int kb = 0; kb < 2; kb++)
                st[kb] = __builtin_amdgcn_mfma_f32_32x32x16_bf16(
                    kfr[kb][s], qf[s], st[kb], 0, 0, 0);
        __builtin_amdgcn_s_setprio(0);

        // ---- V fragments issued now; land under softmax (T14) ----
        bf16x8 vfr[4][4];
        #pragma unroll
        for (int dt = 0; dt < 4; dt++)
            #pragma unroll
            for (int s = 0; s < 4; s++)
                vfr[dt][s] = ld_frag(vptr + (dt * 4 + s) * 512);

        // ---- row max; causal cndmask only on the diagonal tile ----
        float tmx;
        if (kvb + 63 > qwb) {            // wave-uniform: diagonal tile
            const int thr = q - kvb - 4 * hi;   // pass iff kb*32 + 8g + r <= thr
            tmx = -INFINITY;
            #pragma unroll
            for (int kb = 0; kb < 2; kb++)
                #pragma unroll
                for (int g = 0; g < 4; g++)
                    #pragma unroll
                    for (int r = 0; r < 4; r++) {
                        const int e = g * 4 + r;
                        float v = (kb * 32 + 8 * g + r <= thr) ? st[kb][e] : -INFINITY;
                        st[kb][e] = v;
                        tmx = fmaxf(tmx, v);
                    }
        } else {                          // interior: max3-fusible tree
            tmx = fmaxf(st[0][0], st[0][1]);
            #pragma unroll
            for (int e = 2; e < 16; e += 2)
                tmx = fmaxf(fmaxf(tmx, st[0][e]), st[0][e + 1]);
            #pragma unroll
            for (int e = 0; e < 16; e += 2)
                tmx = fmaxf(fmaxf(tmx, st[1][e]), st[1][e + 1]);
        }
        tmx = fmaxf(tmx, __shfl_xor(tmx, 32));
        const float m2x = tmx * C2LOG;

        // ---- online softmax (log2 domain) + T13 defer-max ----
        const bool nosc = __all(m2x <= m_i + 8.0f);
        const float mnew = nosc ? m_i : fmaxf(m_i, m2x);
        float rs = 0.0f;
        #pragma unroll
        for (int kb = 0; kb < 2; kb++)
            #pragma unroll
            for (int e = 0; e < 16; e++) {
                float pv = exp2f(fmaf(st[kb][e], C2LOG, -mnew));
                st[kb][e] = pv;
                rs += pv;
            }
        rs += __shfl_xor(rs, 32);
        if (!nosc) {
            const float alpha = exp2f(m_i - mnew);
            m_i = mnew;
            l_i *= alpha;
            #pragma unroll
            for (int dt = 0; dt < 4; dt++)
                #pragma unroll
                for (int e = 0; e < 16; e++)
                    acc[dt][e] *= alpha;
        }
        l_i += rs;

        // ---- P -> bf16 PV B-frags in registers (T12, HW cvt_pk) ----
        uint4 af[4];
        #pragma unroll
        for (int kb = 0; kb < 2; kb++) {
            unsigned int pk[4][2];
            #pragma unroll
            for (int g = 0; g < 4; g++)
                #pragma unroll
                for (int i = 0; i < 2; i++)
                    pk[g][i] = cvt_pk_bf16(st[kb][g * 4 + 2 * i],
                                           st[kb][g * 4 + 2 * i + 1]);
            #pragma unroll
            for (int sl = 0; sl < 2; sl++) {
                uintx2 r0 = __builtin_amdgcn_permlane32_swap(
                    pk[2 * sl][0], pk[2 * sl + 1][0], false, false);
                uintx2 r1 = __builtin_amdgcn_permlane32_swap(
                    pk[2 * sl][1], pk[2 * sl + 1][1], false, false);
                af[kb * 2 + sl] = make_uint4(r0[0], r1[0], r0[1], r1[1]);
            }
        }

        // ---- O^T += V^T * P^T : 4 d-tiles x 4 kv-steps ----
        __builtin_amdgcn_s_setprio(1);
        #pragma unroll
        for (int s = 0; s < 4; s++) {
            bf16x8 pf = __builtin_bit_cast(bf16x8, af[s]);
            #pragma unroll
            for (int dt = 0; dt < 4; dt++)
                acc[dt] = __builtin_amdgcn_mfma_f32_32x32x16_bf16(
                    vfr[dt][s], pf, acc[dt], 0, 0, 0);
        }
        __builtin_amdgcn_s_setprio(0);

        kptr += 8192; vptr += 8192;
    }

    // ---- epilogue: per-lane q = l31, d = dt*32 + 8g + 4hi + r ----
    const float inv_l = 1.0f / l_i;
    __hip_bfloat16* orow = O + (size_t)(b * SS + q) * 2048 + h * 128;
    #pragma unroll
    for (int dt = 0; dt < 4; dt++)
        #pragma unroll
        for (int g = 0; g < 4; g++) {
            uint2 uu;
            uu.x = cvt_pk_bf16(acc[dt][g * 4 + 0] * inv_l, acc[dt][g * 4 + 1] * inv_l);
            uu.y = cvt_pk_bf16(acc[dt][g * 4 + 2] * inv_l, acc[dt][g * 4 + 3] * inv_l);
            *reinterpret_cast<uint2*>(orow + dt * 32 + 8 * g + 4 * hi) = uu;
        }
}

// ---------------------------------------------------------------------------
extern "C" void kernel_launch(void* const* d_in, const int* in_sizes, int n_in,
                              void* d_out, int out_size, void* d_ws, size_t ws_size,
                              hipStream_t stream)
{
    const float* hs       = (const float*)d_in[0];
    const float* w_kv_d   = (const float*)d_in[1];
    const float* w_q_d    = (const float*)d_in[2];
    const float* w_k_u    = (const float*)d_in[3];
    const float* w_q_u    = (const float*)d_in[4];
    const float* w_v_u    = (const float*)d_in[5];
    const float* w_rope_k = (const float*)d_in[6];
    const float* w_rope_q = (const float*)d_in[7];
    const float* w_o      = (const float*)d_in[8];
    float* out = (float*)d_out;

    char* p = (char*)d_ws;
    auto alloc = [&](size_t nelem) {
        __hip_bfloat16* r = (__hip_bfloat16*)p;
        p += nelem * sizeof(__hip_bfloat16);
        return r;
    };
    __hip_bfloat16* hsb  = alloc((size_t)BS * HID);        // 16 MB (reused as attn)
    __hip_bfloat16* qkvd = alloc((size_t)BS * 512);        // 4 MB
    __hip_bfloat16* WT1  = alloc((size_t)1536 * 2048);     // 6 MB
    __hip_bfloat16* WT2  = alloc((size_t)3072 * 256);      // 1.5 MB
    __hip_bfloat16* WT3  = alloc((size_t)2048 * 256);      // 1 MB
    __hip_bfloat16* WTo  = alloc((size_t)2048 * 2048);     // 8 MB
    __hip_bfloat16* Kf   = alloc((size_t)BS * HID);        // 16 MB, fragment-order K
    __hip_bfloat16* Qbuf = alloc((size_t)BS * HID);        // 16 MB
    __hip_bfloat16* Vf   = alloc((size_t)HID * BS);        // 16 MB, fragment-order V
    __hip_bfloat16* attn = hsb;   // hs dead after G1

    dim3 blk(256);

    // 0. prep: weight transpose+convert (blocks 0..8447) + hs->bf16 (8448..)
    prep_kernel<<<dim3(12544), blk, 0, stream>>>(
        w_kv_d, w_q_d, w_rope_k, w_k_u, w_v_u, w_q_u, w_rope_q, w_o,
        WT1, WT2, WT3, WTo, hs, hsb);

    // G1: [kv_d | q_d | krp] = hsb @ WT1^T  (N=1536, K=2048); krp -> Kf d=64..127
    gemm_bt_kernel<__hip_bfloat16><<<dim3(1536 / 128, BS / 128), blk, 0, stream>>>(
        hsb, 2048, WT1,
        qkvd, 512, 0, 0, 1.0f,
        Kf, 0, 3, 64, 1.0f,
        512, 2048);
    // G2: [k_p | v] = kv_d @ WT2^T  (N=3072, K=256); k_p -> Kf d=0..63, v -> Vf
    gemm_bt_kernel<__hip_bfloat16><<<dim3(3072 / 128, BS / 128), blk, 0, stream>>>(
        qkvd, 512, WT2,
        Kf, 0, 3, 0, 1.0f,
        Vf, 0, 4, 0, 1.0f,
        1024, 256);
    // G3: [q_p | q_rope_pre] = q_d @ WT3^T  (N=2048, K=256)
    gemm_bt_kernel<__hip_bfloat16><<<dim3(2048 / 128, BS / 128), blk, 0, stream>>>(
        qkvd + 256, 512, WT3,
        Qbuf, 2048, 1, 0, 1.0f,
        Qbuf, 2048, 1, 64, 1.0f,
        1024, 256);
    // 4. RoPE in-place (K in Kf layout, Q row-major)
    rope_kernel<<<dim3((BS * NH * 32 + 255) / 256), blk, 0, stream>>>(Kf, Qbuf);
    // 5. flash attention v17 -> attn (no LDS, no barriers, direct L2 frags)
    flash_attn_kernel<<<dim3(8, NH, BB), dim3(512), 0, stream>>>(
        Qbuf, Kf, Vf, attn);
    // G4: out = attn @ WTo^T (fp32 out)
    gemm_bt_kernel<float><<<dim3(2048 / 128, BS / 128), blk, 0, stream>>>(
        attn, 2048, WTo,
        out, 2048, 0, 0, 1.0f,
        out, 2048, 0, 0, 1.0f,
        2048, 2048);
}

// Round 14
// 318.129 us; speedup vs baseline: 4.4140x; 1.0314x over previous
//
#include <hip/hip_runtime.h>
#include <hip/hip_bf16.h>

// Problem constants: B=2, S=2048, HID=2048, H=16, HD=128, HD2=64, LAT=256
#define BB 2
#define SS 2048
#define HID 2048
#define NH 16
#define BS (BB*SS)          // 4096 rows
#define SCALE 0.088388347648318447f   // 1/sqrt(128)
#define C2LOG 0.12751743f              // SCALE * log2(e)

typedef __bf16 bf16x8 __attribute__((ext_vector_type(8)));
typedef float f32x4 __attribute__((ext_vector_type(4)));
typedef float f32x16 __attribute__((ext_vector_type(16)));
typedef unsigned int uintx2 __attribute__((ext_vector_type(2)));

__device__ __forceinline__ bf16x8 ld_frag(const __hip_bfloat16* p) {
    uint4 u = *reinterpret_cast<const uint4*>(p);
    return __builtin_bit_cast(bf16x8, u);
}
// HW packed f32->bf16 convert (RNE). gfx950 has no builtin (m240): inline asm.
__device__ __forceinline__ unsigned int cvt_pk_bf16(float a, float b) {
    unsigned int r;
    asm("v_cvt_pk_bf16_f32 %0, %1, %2" : "=v"(r) : "v"(a), "v"(b));
    return r;
}
__device__ __forceinline__ ushort bf_bits(float v) {
    return (ushort)cvt_pk_bf16(v, v);
}
__device__ __forceinline__ void store_c(__hip_bfloat16* C, size_t idx, float v) {
    *reinterpret_cast<ushort*>(&C[idx]) = bf_bits(v);
}
__device__ __forceinline__ void store_c(float* C, size_t idx, float v) {
    C[idx] = v;
}

// async global->LDS, 16B per lane; lds addr must be wave-uniform base + lane*16
#define GLD16(gp, lp) \
  __builtin_amdgcn_global_load_lds((const __attribute__((address_space(1))) void*)(gp), \
                                   (__attribute__((address_space(3))) void*)(lp), 16, 0, 0)

// ---------------------------------------------------------------------------
// Fragment-order global layouts (v13, kept).
// Kf: element K[b][kv][h][d] ->
//   (b*16+h)*262144 + (kv>>5)*4096 + (d>>4)*512 + ((d>>3)&1)*256 + (kv&31)*8 + (d&7)
// Vf: element V[b][kv][h][d] ->
//   (b*16+h)*262144 + (kv>>6)*8192 + (d>>5)*2048 + ((kv>>4)&3)*512
//   + ((kv>>3)&1)*256 + (d&31)*8 + (kv&7)
// ---------------------------------------------------------------------------

// ---------------------------------------------------------------------------
// prep kernel = weight transpose (blocks 0..8447) + hs fp32->bf16 convert
// (blocks 8448..12543). Block-uniform branch; one launch instead of two.
// ---------------------------------------------------------------------------
__global__ __launch_bounds__(256) void prep_kernel(
    const float* s0, const float* s1, const float* s2, const float* s3,
    const float* s4, const float* s5, const float* s6, const float* s7,
    __hip_bfloat16* WT1, __hip_bfloat16* WT2, __hip_bfloat16* WT3,
    __hip_bfloat16* WTo,
    const float* hs, __hip_bfloat16* hsb)
{
    if (blockIdx.x >= 8448) {
        // convert path: 4096 blocks x 256 threads = 1048576 = BS*HID/8 exact
        int i = (blockIdx.x - 8448) * 256 + threadIdx.x;
        float4 a = reinterpret_cast<const float4*>(hs)[2 * i];
        float4 b = reinterpret_cast<const float4*>(hs)[2 * i + 1];
        uint4 o;
        o.x = cvt_pk_bf16(a.x, a.y);
        o.y = cvt_pk_bf16(a.z, a.w);
        o.z = cvt_pk_bf16(b.x, b.y);
        o.w = cvt_pk_bf16(b.z, b.w);
        reinterpret_cast<uint4*>(hsb)[i] = o;
        return;
    }

    const float* srcs[8] = { s0, s1, s2, s3, s4, s5, s6, s7 };
    const int Rs[8] = { 2048, 2048, 2048, 256, 256, 256, 256, 2048 };
    const int Cs[8] = { 256, 256, 1024, 1024, 2048, 1024, 1024, 2048 };
    __hip_bfloat16* dsts[8] = {
        WT1, WT1 + (size_t)256 * 2048, WT1 + (size_t)512 * 2048,
        WT2, WT2 + (size_t)1024 * 256,
        WT3, WT3 + (size_t)1024 * 256,
        WTo };
    const int prefix[9] = { 0, 512, 1024, 3072, 3328, 3840, 4096, 4352, 8448 };

    int bid = blockIdx.x;
    int seg = 0;
    #pragma unroll
    for (int i = 0; i < 8; i++) if (bid >= prefix[i + 1]) seg = i + 1;
    int local = bid - prefix[seg];
    int R = Rs[seg], C = Cs[seg];
    int tilesC = C / 32;
    int tr = local / tilesC, tc = local % tilesC;
    int r0 = tr * 32, c0 = tc * 32;
    const float* src = srcs[seg];
    __hip_bfloat16* dst = dsts[seg];

    __shared__ float Ts[32][33];
    int t = threadIdx.x;
    int ty = t >> 5, tx = t & 31;
    #pragma unroll
    for (int k = 0; k < 4; k++) {
        int r = ty + k * 8;
        Ts[r][tx] = src[(size_t)(r0 + r) * C + c0 + tx];
    }
    __syncthreads();
    #pragma unroll
    for (int k = 0; k < 4; k++) {
        int r = ty + k * 8;
        *reinterpret_cast<ushort*>(&dst[(size_t)(c0 + r) * R + r0 + tx]) =
            bf_bits(Ts[tx][r]);
    }
}

// ---------------------------------------------------------------------------
// m97-style GEMM + r13 change: DOUBLE-BUFFERED single-barrier K-loop (the
// v13-flash schedule, T3 "minimum 2-phase" recipe). Old loop was
// {sync; stage; sync(full vmcnt(0) drain of JUST-issued loads); compute} —
// the documented m97 ~20% barrier-drain stall. New loop:
// {vmcnt(0) [loads issued a full compute-phase ago => ~zero drain]; barrier
// [tile kt visible AND par^1 free]; stage kt+1 -> par^1; compute par}.
// LDS 16->32KB (still >=4 blocks/CU at VGPR ~104). Epilogues unchanged.
// Epilogue routing: col < splitN -> (C0,...) else (C1,...). cm = output scale.
//   s64==0: plain col
//   s64==1: col c -> (c>>6)*128 + (c&63) + off (head scatter, row-major)
//   s64==2: transposed store: Cp[c*4096 + row]
//   s64==3: Kf fragment-order scatter; c: h=c>>6, d=off+(c&63); row m: b,kv
//   s64==4: Vf fragment-order scatter; c: h=c>>7, d=c&127;    row m: b,kv
// ---------------------------------------------------------------------------
template <typename TC>
__global__ __launch_bounds__(256) void gemm_bt_kernel(
    const __hip_bfloat16* __restrict__ A, int lda,
    const __hip_bfloat16* __restrict__ Bt,
    TC* __restrict__ C0, int ldc0, int sp0, int off0, float cm0,
    TC* __restrict__ C1, int ldc1, int sp1, int off1, float cm1,
    int splitN, int K)
{
    __shared__ alignas(16) __hip_bfloat16 As[2 * 128 * 32];
    __shared__ alignas(16) __hip_bfloat16 Bs[2 * 128 * 32];

    // XCD-aware bijective remap (nwg % 8 == 0 for all launches here)
    const int nwg = gridDim.x * gridDim.y;
    int lin = blockIdx.y * gridDim.x + blockIdx.x;
    lin = (lin & 7) * (nwg >> 3) + (lin >> 3);
    const int bn = (lin % gridDim.x) * 128;
    const int bm = (lin / gridDim.x) * 128;

    const int t = threadIdx.x;
    const int w = t >> 6;
    const int lane = t & 63;
    const int l15 = lane & 15;
    const int quad = lane >> 4;
    const int wm = (w & 1) * 64;
    const int wn = (w >> 1) * 64;

    const int srow = lane >> 2;          // 0..15
    const int skcol = (lane & 3) * 8;    // 0,8,16,24

    f32x4 acc[4][4] = {};

    // prologue: stage tile k0=0 into buf 0
    #pragma unroll
    for (int i = 0; i < 2; i++) {
        int r = w * 32 + i * 16 + srow;
        GLD16(A + (size_t)(bm + r) * lda + skcol, &As[r * 32 + skcol]);
        GLD16(Bt + (size_t)(bn + r) * K + skcol, &Bs[r * 32 + skcol]);
    }

    for (int k0 = 0; k0 < K; k0 += 32) {
        const int par = (k0 >> 5) & 1;

        asm volatile("s_waitcnt vmcnt(0)" ::: "memory");  // tile-k0 loads (stale) done
        __builtin_amdgcn_s_barrier();   // tile k0 visible block-wide; buf par^1 free
        asm volatile("" ::: "memory");

        if (k0 + 32 < K) {              // stage tile k0+32 into par^1
            const int pn = (par ^ 1) * 4096;
            #pragma unroll
            for (int i = 0; i < 2; i++) {
                int r = w * 32 + i * 16 + srow;
                GLD16(A + (size_t)(bm + r) * lda + k0 + 32 + skcol,
                      &As[pn + r * 32 + skcol]);
                GLD16(Bt + (size_t)(bn + r) * K + k0 + 32 + skcol,
                      &Bs[pn + r * 32 + skcol]);
            }
        }

        const __hip_bfloat16* Ab = &As[par * 4096];
        const __hip_bfloat16* Bb = &Bs[par * 4096];
        bf16x8 af[4], bf[4];
        #pragma unroll
        for (int mt = 0; mt < 4; mt++)
            af[mt] = ld_frag(Ab + (wm + mt * 16 + l15) * 32 + quad * 8);
        #pragma unroll
        for (int nt = 0; nt < 4; nt++)
            bf[nt] = ld_frag(Bb + (wn + nt * 16 + l15) * 32 + quad * 8);
        #pragma unroll
        for (int mt = 0; mt < 4; mt++)
            #pragma unroll
            for (int nt = 0; nt < 4; nt++)
                acc[mt][nt] = __builtin_amdgcn_mfma_f32_16x16x32_bf16(
                    af[mt], bf[nt], acc[mt][nt], 0, 0, 0);
    }

    #pragma unroll
    for (int nt = 0; nt < 4; nt++) {
        int col = bn + wn + nt * 16 + l15;
        TC* Cp; int c, ld, s64, off; float cm;
        if (col < splitN) { Cp = C0; c = col; ld = ldc0; s64 = sp0; off = off0; cm = cm0; }
        else { Cp = C1; c = col - splitN; ld = ldc1; s64 = sp1; off = off1; cm = cm1; }
        if (s64 == 2) {
            #pragma unroll
            for (int mt = 0; mt < 4; mt++) {
                int row0 = bm + wm + mt * 16 + quad * 4;
                #pragma unroll
                for (int r = 0; r < 4; r++)
                    store_c(Cp, (size_t)c * 4096 + row0 + r, acc[mt][nt][r] * cm);
            }
        } else if (s64 == 3) {
            const int hh = c >> 6, d = off + (c & 63);
            const size_t dbase = (size_t)(d >> 4) * 512
                               + (size_t)((d >> 3) & 1) * 256 + (d & 7);
            #pragma unroll
            for (int mt = 0; mt < 4; mt++) {
                #pragma unroll
                for (int r = 0; r < 4; r++) {
                    int m = bm + wm + mt * 16 + quad * 4 + r;
                    int bb2 = m >> 11, kv = m & 2047;
                    size_t idx = (size_t)(bb2 * 16 + hh) * 262144
                               + (size_t)(kv >> 5) * 4096 + dbase
                               + (size_t)(kv & 31) * 8;
                    store_c(Cp, idx, acc[mt][nt][r] * cm);
                }
            }
        } else if (s64 == 4) {
            const int hh = c >> 7, d = c & 127;
            const size_t dbase = (size_t)(d >> 5) * 2048 + (size_t)(d & 31) * 8;
            #pragma unroll
            for (int mt = 0; mt < 4; mt++) {
                #pragma unroll
                for (int r = 0; r < 4; r++) {
                    int m = bm + wm + mt * 16 + quad * 4 + r;
                    int bb2 = m >> 11, kv = m & 2047;
                    size_t idx = (size_t)(bb2 * 16 + hh) * 262144
                               + (size_t)(kv >> 6) * 8192 + dbase
                               + (size_t)((kv >> 4) & 3) * 512
                               + (size_t)((kv >> 3) & 1) * 256 + (kv & 7);
                    store_c(Cp, idx, acc[mt][nt][r] * cm);
                }
            }
        } else {
            int oc = s64 ? ((c >> 6) * 128 + (c & 63) + off) : c;
            #pragma unroll
            for (int mt = 0; mt < 4; mt++) {
                #pragma unroll
                for (int r = 0; r < 4; r++) {
                    int row = bm + wm + mt * 16 + quad * 4 + r;
                    store_c(Cp, (size_t)row * ld + oc, acc[mt][nt][r] * cm);
                }
            }
        }
    }
}

// ---------------------------------------------------------------------------
// RoPE in-place: K in Kf fragment-order layout, Q in row-major Qbuf.
// Pair (d1=64+i, d2=96+i): in Kf, d2 is exactly +2 regions = +1024 elems.
// ---------------------------------------------------------------------------
__global__ __launch_bounds__(256) void rope_kernel(
    __hip_bfloat16* __restrict__ Kf, __hip_bfloat16* __restrict__ Qb)
{
    int idx = blockIdx.x * blockDim.x + threadIdx.x;
    if (idx >= BS * NH * 32) return;
    int i = idx & 31;
    int h = (idx >> 5) & 15;
    int row = idx >> 9;
    int s = row & (SS - 1);
    int b = row >> 11;

    float inv = exp2f(-(float)i * 0.4152410118609203f);  // 10000^(-i/32)
    float ang = (float)s * inv;
    float sn = sinf(ang), cs = cosf(ang);

    {   // K (Kf layout)
        size_t kaddr = ((size_t)(b * 16 + h) * 64 + (s >> 5)) * 4096
                     + (size_t)(4 + (i >> 4)) * 512
                     + (size_t)(((i >> 3) & 1) * 32 + (s & 31)) * 8 + (i & 7);
        float x1 = __bfloat162float(Kf[kaddr]);
        float x2 = __bfloat162float(Kf[kaddr + 1024]);
        *reinterpret_cast<ushort*>(&Kf[kaddr])        = bf_bits(x1 * cs - x2 * sn);
        *reinterpret_cast<ushort*>(&Kf[kaddr + 1024]) = bf_bits(x1 * sn + x2 * cs);
    }
    {   // Q (row-major)
        size_t obase = (size_t)row * 2048 + h * 128 + 64 + i;
        float x1 = __bfloat162float(Qb[obase]);
        float x2 = __bfloat162float(Qb[obase + 32]);
        *reinterpret_cast<ushort*>(&Qb[obase])      = bf_bits(x1 * cs - x2 * sn);
        *reinterpret_cast<ushort*>(&Qb[obase + 32]) = bf_bits(x1 * sn + x2 * cs);
    }
}

// ---------------------------------------------------------------------------
// Flash attention v17 (verbatim — 67.0us, VGPR 108, LDS 0, FETCH 24.6MB
// re-confirmed in r13).
// ---------------------------------------------------------------------------
__global__ __launch_bounds__(512) void flash_attn_kernel(
    const __hip_bfloat16* __restrict__ Q,
    const __hip_bfloat16* __restrict__ Kf,
    const __hip_bfloat16* __restrict__ Vf,
    __hip_bfloat16* __restrict__ O)
{
    // XCD-grouped decode: same-(b,h) blocks share blockIdx.x -> same XCD.
    const int p = blockIdx.y & 7;                     // pair index 0..7
    const int h = blockIdx.x + 8 * (blockIdx.y >> 3); // head 0..15
    const int b = blockIdx.z;
    const int t = threadIdx.x;
    const int w = t >> 6;                // 0..7
    const int lane = t & 63;
    const int l31 = lane & 31;
    const int hi = lane >> 5;

    const int qt = (w < 4) ? (15 - p) : p;   // this wave's q-tile
    const int wq = w & 3;
    const int qwb = qt * 128 + wq * 32;      // wave's q base (32 rows)
    const int q = qwb + l31;                 // this lane's q row
    const int my_nt = 2 * qt + 1 + (wq >> 1);// kv tiles this wave needs

    const __hip_bfloat16* Kfb = Kf + (size_t)(b * 16 + h) * 262144;
    const __hip_bfloat16* Vfb = Vf + (size_t)(b * 16 + h) * 262144;

    // Q B-frags: qf[s] = Q[q][d = 16s + 8hi + j], j=0..7
    bf16x8 qf[8];
    {
        const __hip_bfloat16* qrow = Q + (size_t)(b * SS + q) * 2048 + h * 128;
        #pragma unroll
        for (int s = 0; s < 8; s++)
            qf[s] = ld_frag(qrow + s * 16 + hi * 8);
    }

    const int loff = lane * 8;               // fragment slot (elements)
    const __hip_bfloat16* kptr = Kfb + loff; // region (kb*8+s)*512 per tile
    const __hip_bfloat16* vptr = Vfb + loff; // region (dt*4+s)*512 per tile

    float m_i = -INFINITY;   // running max, log2 domain (S * C2LOG)
    float l_i = 0.0f;
    f32x16 acc[4] = {};      // O^T: acc[dt], d = dt*32 + 8*(e>>2) + 4hi + (e&3), col q=l31

    for (int kt = 0; kt < my_nt; kt++) {
        const int kvb = kt * 64;

        // ---- K fragments: 16 coalesced 16B/lane loads straight from L2 ----
        bf16x8 kfr[2][8];
        #pragma unroll
        for (int kb = 0; kb < 2; kb++)
            #pragma unroll
            for (int s = 0; s < 8; s++)
                kfr[kb][s] = ld_frag(kptr + (kb * 8 + s) * 512);

        // ---- S^T = K * Q^T : 2 kv-blocks x 8 k-steps of 32x32x16 ----
        f32x16 st[2] = {};
        __builtin_amdgcn_s_setprio(1);
        #pragma unroll
        for (int s = 0; s < 8; s++)
            #pragma unroll
            for (int kb = 0; kb < 2; kb++)
                st[kb] = __builtin_amdgcn_mfma_f32_32x32x16_bf16(
                    kfr[kb][s], qf[s], st[kb], 0, 0, 0);
        __builtin_amdgcn_s_setprio(0);

        // ---- V fragments issued now; land under softmax (T14) ----
        bf16x8 vfr[4][4];
        #pragma unroll
        for (int dt = 0; dt < 4; dt++)
            #pragma unroll
            for (int s = 0; s < 4; s++)
                vfr[dt][s] = ld_frag(vptr + (dt * 4 + s) * 512);

        // ---- row max; causal cndmask only on the diagonal tile ----
        float tmx;
        if (kvb + 63 > qwb) {            // wave-uniform: diagonal tile
            const int thr = q - kvb - 4 * hi;   // pass iff kb*32 + 8g + r <= thr
            tmx = -INFINITY;
            #pragma unroll
            for (int kb = 0; kb < 2; kb++)
                #pragma unroll
                for (int g = 0; g < 4; g++)
                    #pragma unroll
                    for (int r = 0; r < 4; r++) {
                        const int e = g * 4 + r;
                        float v = (kb * 32 + 8 * g + r <= thr) ? st[kb][e] : -INFINITY;
                        st[kb][e] = v;
                        tmx = fmaxf(tmx, v);
                    }
        } else {                          // interior: max3-fusible tree
            tmx = fmaxf(st[0][0], st[0][1]);
            #pragma unroll
            for (int e = 2; e < 16; e += 2)
                tmx = fmaxf(fmaxf(tmx, st[0][e]), st[0][e + 1]);
            #pragma unroll
            for (int e = 0; e < 16; e += 2)
                tmx = fmaxf(fmaxf(tmx, st[1][e]), st[1][e + 1]);
        }
        tmx = fmaxf(tmx, __shfl_xor(tmx, 32));
        const float m2x = tmx * C2LOG;

        // ---- online softmax (log2 domain) + T13 defer-max ----
        const bool nosc = __all(m2x <= m_i + 8.0f);
        const float mnew = nosc ? m_i : fmaxf(m_i, m2x);
        float rs = 0.0f;
        #pragma unroll
        for (int kb = 0; kb < 2; kb++)
            #pragma unroll
            for (int e = 0; e < 16; e++) {
                float pv = exp2f(fmaf(st[kb][e], C2LOG, -mnew));
                st[kb][e] = pv;
                rs += pv;
            }
        rs += __shfl_xor(rs, 32);
        if (!nosc) {
            const float alpha = exp2f(m_i - mnew);
            m_i = mnew;
            l_i *= alpha;
            #pragma unroll
            for (int dt = 0; dt < 4; dt++)
                #pragma unroll
                for (int e = 0; e < 16; e++)
                    acc[dt][e] *= alpha;
        }
        l_i += rs;

        // ---- P -> bf16 PV B-frags in registers (T12, HW cvt_pk) ----
        uint4 af[4];
        #pragma unroll
        for (int kb = 0; kb < 2; kb++) {
            unsigned int pk[4][2];
            #pragma unroll
            for (int g = 0; g < 4; g++)
                #pragma unroll
                for (int i = 0; i < 2; i++)
                    pk[g][i] = cvt_pk_bf16(st[kb][g * 4 + 2 * i],
                                           st[kb][g * 4 + 2 * i + 1]);
            #pragma unroll
            for (int sl = 0; sl < 2; sl++) {
                uintx2 r0 = __builtin_amdgcn_permlane32_swap(
                    pk[2 * sl][0], pk[2 * sl + 1][0], false, false);
                uintx2 r1 = __builtin_amdgcn_permlane32_swap(
                    pk[2 * sl][1], pk[2 * sl + 1][1], false, false);
                af[kb * 2 + sl] = make_uint4(r0[0], r1[0], r0[1], r1[1]);
            }
        }

        // ---- O^T += V^T * P^T : 4 d-tiles x 4 kv-steps ----
        __builtin_amdgcn_s_setprio(1);
        #pragma unroll
        for (int s = 0; s < 4; s++) {
            bf16x8 pf = __builtin_bit_cast(bf16x8, af[s]);
            #pragma unroll
            for (int dt = 0; dt < 4; dt++)
                acc[dt] = __builtin_amdgcn_mfma_f32_32x32x16_bf16(
                    vfr[dt][s], pf, acc[dt], 0, 0, 0);
        }
        __builtin_amdgcn_s_setprio(0);

        kptr += 8192; vptr += 8192;
    }

    // ---- epilogue: per-lane q = l31, d = dt*32 + 8g + 4hi + r ----
    const float inv_l = 1.0f / l_i;
    __hip_bfloat16* orow = O + (size_t)(b * SS + q) * 2048 + h * 128;
    #pragma unroll
    for (int dt = 0; dt < 4; dt++)
        #pragma unroll
        for (int g = 0; g < 4; g++) {
            uint2 uu;
            uu.x = cvt_pk_bf16(acc[dt][g * 4 + 0] * inv_l, acc[dt][g * 4 + 1] * inv_l);
            uu.y = cvt_pk_bf16(acc[dt][g * 4 + 2] * inv_l, acc[dt][g * 4 + 3] * inv_l);
            *reinterpret_cast<uint2*>(orow + dt * 32 + 8 * g + 4 * hi) = uu;
        }
}

// ---------------------------------------------------------------------------
extern "C" void kernel_launch(void* const* d_in, const int* in_sizes, int n_in,
                              void* d_out, int out_size, void* d_ws, size_t ws_size,
                              hipStream_t stream)
{
    const float* hs       = (const float*)d_in[0];
    const float* w_kv_d   = (const float*)d_in[1];
    const float* w_q_d    = (const float*)d_in[2];
    const float* w_k_u    = (const float*)d_in[3];
    const float* w_q_u    = (const float*)d_in[4];
    const float* w_v_u    = (const float*)d_in[5];
    const float* w_rope_k = (const float*)d_in[6];
    const float* w_rope_q = (const float*)d_in[7];
    const float* w_o      = (const float*)d_in[8];
    float* out = (float*)d_out;

    char* p = (char*)d_ws;
    auto alloc = [&](size_t nelem) {
        __hip_bfloat16* r = (__hip_bfloat16*)p;
        p += nelem * sizeof(__hip_bfloat16);
        return r;
    };
    __hip_bfloat16* hsb  = alloc((size_t)BS * HID);        // 16 MB (reused as attn)
    __hip_bfloat16* qkvd = alloc((size_t)BS * 512);        // 4 MB
    __hip_bfloat16* WT1  = alloc((size_t)1536 * 2048);     // 6 MB
    __hip_bfloat16* WT2  = alloc((size_t)3072 * 256);      // 1.5 MB
    __hip_bfloat16* WT3  = alloc((size_t)2048 * 256);      // 1 MB
    __hip_bfloat16* WTo  = alloc((size_t)2048 * 2048);     // 8 MB
    __hip_bfloat16* Kf   = alloc((size_t)BS * HID);        // 16 MB, fragment-order K
    __hip_bfloat16* Qbuf = alloc((size_t)BS * HID);        // 16 MB
    __hip_bfloat16* Vf   = alloc((size_t)HID * BS);        // 16 MB, fragment-order V
    __hip_bfloat16* attn = hsb;   // hs dead after G1

    dim3 blk(256);

    // 0. prep: weight transpose+convert (blocks 0..8447) + hs->bf16 (8448..)
    prep_kernel<<<dim3(12544), blk, 0, stream>>>(
        w_kv_d, w_q_d, w_rope_k, w_k_u, w_v_u, w_q_u, w_rope_q, w_o,
        WT1, WT2, WT3, WTo, hs, hsb);

    // G1: [kv_d | q_d | krp] = hsb @ WT1^T  (N=1536, K=2048); krp -> Kf d=64..127
    gemm_bt_kernel<__hip_bfloat16><<<dim3(1536 / 128, BS / 128), blk, 0, stream>>>(
        hsb, 2048, WT1,
        qkvd, 512, 0, 0, 1.0f,
        Kf, 0, 3, 64, 1.0f,
        512, 2048);
    // G2: [k_p | v] = kv_d @ WT2^T  (N=3072, K=256); k_p -> Kf d=0..63, v -> Vf
    gemm_bt_kernel<__hip_bfloat16><<<dim3(3072 / 128, BS / 128), blk, 0, stream>>>(
        qkvd, 512, WT2,
        Kf, 0, 3, 0, 1.0f,
        Vf, 0, 4, 0, 1.0f,
        1024, 256);
    // G3: [q_p | q_rope_pre] = q_d @ WT3^T  (N=2048, K=256)
    gemm_bt_kernel<__hip_bfloat16><<<dim3(2048 / 128, BS / 128), blk, 0, stream>>>(
        qkvd + 256, 512, WT3,
        Qbuf, 2048, 1, 0, 1.0f,
        Qbuf, 2048, 1, 64, 1.0f,
        1024, 256);
    // 4. RoPE in-place (K in Kf layout, Q row-major)
    rope_kernel<<<dim3((BS * NH * 32 + 255) / 256), blk, 0, stream>>>(Kf, Qbuf);
    // 5. flash attention v17 -> attn (no LDS, no barriers, direct L2 frags)
    flash_attn_kernel<<<dim3(8, NH, BB), dim3(512), 0, stream>>>(
        Qbuf, Kf, Vf, attn);
    // G4: out = attn @ WTo^T (fp32 out)
    gemm_bt_kernel<float><<<dim3(2048 / 128, BS / 128), blk, 0, stream>>>(
        attn, 2048, WTo,
        out, 2048, 0, 0, 1.0f,
        out, 2048, 0, 0, 1.0f,
        2048, 2048);
}